// Round 4
// baseline (92.630 us; speedup 1.0000x reference)
//
#include <hip/hip_runtime.h>

#define NGRID 257
#define LDS_PITCH 260                      // halfs per row; 520 B stride = 65 x 8B
#define LDS_BYTES (LDS_PITCH * NGRID * 2)  // 133640 B < 160 KiB
#define BLOCK 1024
#define GRID 128                           // DIAGNOSTIC: 2x work/CU -> kernel visible in rocprof top-5
#define OUTER 16                           // 2 points/iter: 128*1024*32 == 4,194,304 exactly

typedef _Float16 half2_t __attribute__((ext_vector_type(2)));
typedef _Float16 half4_t __attribute__((ext_vector_type(4)));
typedef float    f32x2  __attribute__((ext_vector_type(2)));

// 4-byte-aligned float4 view (coe rows have odd stride 257)
struct __attribute__((packed, aligned(4))) f4u { float x, y, z, w; };

__device__ __forceinline__ half2_t pack2(float a, float b) {
    return __builtin_bit_cast(half2_t, __builtin_amdgcn_cvt_pkrtz(a, b));
}

// Per-grid-index Lagrange denominator reciprocal: d(j) for j = g mod 4.
__device__ __forceinline__ float rowscale(int r) {
    return (r & 1) ? (-1.0f / 6.0f) : ((r & 2) ? 0.25f : (1.0f / 24.0f));
}

// Packed numerator basis for both dims of one point (denoms folded into LDS coe).
__device__ __forceinline__ void nbasis(f32x2 fr, f32x2 n[5]) {
    f32x2 f0 = fr * 4.0f;
    f32x2 f1 = f0 - 1.0f;
    f32x2 f2 = f0 - 2.0f;
    f32x2 f3 = f1 - 2.0f;
    f32x2 f4 = f0 - 4.0f;
    f32x2 p01 = f0 * f1;
    f32x2 p12 = f1 * f2;
    f32x2 p23 = f2 * f3;
    f32x2 p34 = f3 * f4;
    n[0] = p12 * p34;
    n[1] = (f0 * f2) * p34;
    n[2] = p01 * p34;
    n[3] = p01 * (f2 * f4);
    n[4] = p01 * p23;
}

// TWO points per call: 12 DS gathers issued back-to-back, two independent
// dot chains (R3 body, unchanged -- this round varies ONLY the grid).
__device__ __forceinline__ float2 eval2(const _Float16* __restrict__ lds,
                                        float xa0, float xa1,
                                        float xb0, float xb1) {
    float ua0 = xa0 * 64.0f, ua1 = xa1 * 64.0f;
    float ub0 = xb0 * 64.0f, ub1 = xb1 * 64.0f;
    int ia0 = (int)ua0, ia1 = (int)ua1;
    int ib0 = (int)ub0, ib1 = (int)ub1;
    f32x2 frA = { __builtin_amdgcn_fractf(ua0), __builtin_amdgcn_fractf(ua1) };
    f32x2 frB = { __builtin_amdgcn_fractf(ub0), __builtin_amdgcn_fractf(ub1) };

    const _Float16* baseA  = lds + (ia0 * 4) * LDS_PITCH + ia1 * 4;
    const _Float16* baseA2 = baseA + 2 * LDS_PITCH;
    const _Float16* baseB  = lds + (ib0 * 4) * LDS_PITCH + ib1 * 4;
    const _Float16* baseB2 = baseB + 2 * LDS_PITCH;

    // ---- 12 gathers, program-order adjacent ----
    half4_t la0 = *(const half4_t*)(baseA);
    half4_t la1 = *(const half4_t*)(baseA + LDS_PITCH);
    half4_t la2 = *(const half4_t*)(baseA2);
    half4_t la3 = *(const half4_t*)(baseA2 + LDS_PITCH);
    half4_t la4 = *(const half4_t*)(baseA2 + 2 * LDS_PITCH);
    half2_t ha0 = *(const half2_t*)(baseA + 4);
    half2_t ha1 = *(const half2_t*)(baseA + LDS_PITCH + 4);
    half2_t ha2 = *(const half2_t*)(baseA2 + 4);
    half2_t ha3 = *(const half2_t*)(baseA2 + LDS_PITCH + 4);
    half2_t ha4 = *(const half2_t*)(baseA2 + 2 * LDS_PITCH + 4);

    half4_t lb0 = *(const half4_t*)(baseB);
    half4_t lb1 = *(const half4_t*)(baseB + LDS_PITCH);
    half4_t lb2 = *(const half4_t*)(baseB2);
    half4_t lb3 = *(const half4_t*)(baseB2 + LDS_PITCH);
    half4_t lb4 = *(const half4_t*)(baseB2 + 2 * LDS_PITCH);
    half2_t hb0 = *(const half2_t*)(baseB + 4);
    half2_t hb1 = *(const half2_t*)(baseB + LDS_PITCH + 4);
    half2_t hb2 = *(const half2_t*)(baseB2 + 4);
    half2_t hb3 = *(const half2_t*)(baseB2 + LDS_PITCH + 4);
    half2_t hb4 = *(const half2_t*)(baseB2 + 2 * LDS_PITCH + 4);

    // ---- bases for both points (VALU overlaps DS latency) ----
    f32x2 nA[5], nB[5];
    nbasis(frA, nA);
    nbasis(frB, nB);
    half2_t qA01 = pack2(nA[0][1], nA[1][1]);
    half2_t qA23 = pack2(nA[2][1], nA[3][1]);
    float   bA4  = nA[4][1];
    half2_t qB01 = pack2(nB[0][1], nB[1][1]);
    half2_t qB23 = pack2(nB[2][1], nB[3][1]);
    float   bB4  = nB[4][1];

    half4_t loA[5] = { la0, la1, la2, la3, la4 };
    half2_t hiA[5] = { ha0, ha1, ha2, ha3, ha4 };
    half4_t loB[5] = { lb0, lb1, lb2, lb3, lb4 };
    half2_t hiB[5] = { hb0, hb1, hb2, hb3, hb4 };

    float rdA[5], rdB[5];
#pragma unroll
    for (int i = 0; i < 5; ++i) {
        half2_t xy = __builtin_shufflevector(loA[i], loA[i], 0, 1);
        half2_t zw = __builtin_shufflevector(loA[i], loA[i], 2, 3);
        float r = (float)hiA[i][0] * bA4;
        r = __builtin_amdgcn_fdot2(zw, qA23, r, false);
        r = __builtin_amdgcn_fdot2(xy, qA01, r, false);
        rdA[i] = r;
    }
#pragma unroll
    for (int i = 0; i < 5; ++i) {
        half2_t xy = __builtin_shufflevector(loB[i], loB[i], 0, 1);
        half2_t zw = __builtin_shufflevector(loB[i], loB[i], 2, 3);
        float r = (float)hiB[i][0] * bB4;
        r = __builtin_amdgcn_fdot2(zw, qB23, r, false);
        r = __builtin_amdgcn_fdot2(xy, qB01, r, false);
        rdB[i] = r;
    }

    float accA = nA[4][0] * rdA[4];
    accA = fmaf(nA[0][0], rdA[0], accA);
    accA = fmaf(nA[2][0], rdA[2], accA);
    float accA2 = nA[1][0] * rdA[1];
    accA2 = fmaf(nA[3][0], rdA[3], accA2);

    float accB = nB[4][0] * rdB[4];
    accB = fmaf(nB[0][0], rdB[0], accB);
    accB = fmaf(nB[2][0], rdB[2], accB);
    float accB2 = nB[1][0] * rdB[1];
    accB2 = fmaf(nB[3][0], rdB[3], accB2);

    float2 r;
    r.x = accA + accA2;
    r.y = accB + accB2;
    return r;
}

__launch_bounds__(BLOCK, 4)   // VGPR<=128; single 133KB-LDS block, 16 waves/CU
__global__ void lagrange_kernel(const float* __restrict__ inputs,
                                const float* __restrict__ coe,
                                float* __restrict__ out,
                                int npts) {
    extern __shared__ _Float16 lds[];
    const int t = threadIdx.x;

    // --- branch-free staging with denominator folding (R2, neutral-verified) ---
#pragma unroll
    for (int k = 0; k < 16; ++k) {
        int g = t + k * BLOCK;          // 0..16383: rows 0..255 complete
        int r = g >> 6;
        int c4 = (g & 63) << 2;
        f4u q = *(const f4u*)(coe + r * NGRID + c4);
        float rs = rowscale(r);
        half4_t h = { (_Float16)(q.x * (rs * (1.0f / 24.0f))),
                      (_Float16)(q.y * (rs * (-1.0f / 6.0f))),
                      (_Float16)(q.z * (rs * 0.25f)),
                      (_Float16)(q.w * (rs * (-1.0f / 6.0f))) };
        *(half4_t*)(lds + r * LDS_PITCH + c4) = h;
    }
    if (t < 64) {                       // row 256 (scale 1/24), quads 0..63
        int c4 = t << 2;
        f4u q = *(const f4u*)(coe + 256 * NGRID + c4);
        const float rs = 1.0f / 24.0f;
        half4_t h = { (_Float16)(q.x * (rs * (1.0f / 24.0f))),
                      (_Float16)(q.y * (rs * (-1.0f / 6.0f))),
                      (_Float16)(q.z * (rs * 0.25f)),
                      (_Float16)(q.w * (rs * (-1.0f / 6.0f))) };
        *(half4_t*)(lds + 256 * LDS_PITCH + c4) = h;
    }
    if (t < NGRID) {                    // column 256 (scale 1/24), all 257 rows
        float rs = rowscale(t);
        lds[t * LDS_PITCH + 256] = (_Float16)(coe[t * NGRID + 256] * (rs * (1.0f / 24.0f)));
    }
    __syncthreads();

    const float2* __restrict__ in2 = (const float2*)inputs;  // 1 point / float2
    const int tid = blockIdx.x * BLOCK + t;
    const int stride = GRID * BLOCK;                         // 131072
    (void)npts;   // npts == GRID*BLOCK*32 exactly -> no bounds checks

    // Two point streams (k and k+OUTER), 3-deep input prefetch each.
    float2 a0 = in2[tid];
    float2 a1 = in2[tid + stride];
    float2 a2 = in2[tid + 2 * stride];
    float2 b0 = in2[tid + OUTER * stride];
    float2 b1 = in2[tid + (OUTER + 1) * stride];
    float2 b2 = in2[tid + (OUTER + 2) * stride];
#pragma unroll
    for (int k = 0; k < OUTER; ++k) {
        float2 a3, b3;
        if (k + 3 < OUTER) {
            a3 = in2[tid + (k + 3) * stride];
            b3 = in2[tid + (k + OUTER + 3) * stride];
        }
        float2 r = eval2(lds, a0.x, a0.y, b0.x, b0.y);
        __builtin_nontemporal_store(r.x, &out[tid + k * stride]);
        __builtin_nontemporal_store(r.y, &out[tid + (k + OUTER) * stride]);
        a0 = a1; a1 = a2; a2 = a3;
        b0 = b1; b1 = b2; b2 = b3;
    }
}

extern "C" void kernel_launch(void* const* d_in, const int* in_sizes, int n_in,
                              void* d_out, int out_size, void* d_ws, size_t ws_size,
                              hipStream_t stream) {
    const float* inputs = (const float*)d_in[0];   // (2048,2048,2) f32
    const float* coe    = (const float*)d_in[1];   // (257,257) f32
    float* out = (float*)d_out;                    // (2048,2048) f32
    int npts = out_size;                           // 4,194,304

    (void)hipFuncSetAttribute((const void*)lagrange_kernel,
                              hipFuncAttributeMaxDynamicSharedMemorySize,
                              LDS_BYTES);

    dim3 grid(GRID), block(BLOCK);   // 1 block/CU, 128 of 256 CUs: DIAGNOSTIC round
    hipLaunchKernelGGL(lagrange_kernel, grid, block, LDS_BYTES, stream,
                       inputs, coe, out, npts);
}

// Round 5
// 86.041 us; speedup vs baseline: 1.0766x; 1.0766x over previous
//
#include <hip/hip_runtime.h>

#define NGRID 257
#define LDS_PITCH 260                      // halfs per row; 520 B stride = 65 x 8B
#define LDS_BYTES (LDS_PITCH * NGRID * 2)  // 133640 B < 160 KiB
#define BLOCK 1024
#define GRID 256
#define OUTER 8                            // 2 points/iter: 256*1024*16 == 4,194,304 exactly

typedef _Float16 half2_t __attribute__((ext_vector_type(2)));
typedef _Float16 half4_t __attribute__((ext_vector_type(4)));
typedef float    f32x2  __attribute__((ext_vector_type(2)));

// 4-byte-aligned float4 view (coe rows have odd stride 257)
struct __attribute__((packed, aligned(4))) f4u { float x, y, z, w; };

__device__ __forceinline__ half2_t pack2(float a, float b) {
    return __builtin_bit_cast(half2_t, __builtin_amdgcn_cvt_pkrtz(a, b));
}

// Per-grid-index Lagrange denominator reciprocal: d(j) for j = g mod 4.
__device__ __forceinline__ float rowscale(int r) {
    return (r & 1) ? (-1.0f / 6.0f) : ((r & 2) ? 0.25f : (1.0f / 24.0f));
}

// Packed numerator basis for both dims of one point (denoms folded into LDS coe).
__device__ __forceinline__ void nbasis(f32x2 fr, f32x2 n[5]) {
    f32x2 f0 = fr * 4.0f;
    f32x2 f1 = f0 - 1.0f;
    f32x2 f2 = f0 - 2.0f;
    f32x2 f3 = f1 - 2.0f;
    f32x2 f4 = f0 - 4.0f;
    f32x2 p01 = f0 * f1;
    f32x2 p12 = f1 * f2;
    f32x2 p23 = f2 * f3;
    f32x2 p34 = f3 * f4;
    n[0] = p12 * p34;
    n[1] = (f0 * f2) * p34;
    n[2] = p01 * p34;
    n[3] = p01 * (f2 * f4);
    n[4] = p01 * p23;
}

// TWO points per call: 12 DS gathers issued back-to-back, two independent
// dot chains (R3 body, unchanged -- this round varies ONLY the prologue).
__device__ __forceinline__ float2 eval2(const _Float16* __restrict__ lds,
                                        float xa0, float xa1,
                                        float xb0, float xb1) {
    float ua0 = xa0 * 64.0f, ua1 = xa1 * 64.0f;
    float ub0 = xb0 * 64.0f, ub1 = xb1 * 64.0f;
    int ia0 = (int)ua0, ia1 = (int)ua1;
    int ib0 = (int)ub0, ib1 = (int)ub1;
    f32x2 frA = { __builtin_amdgcn_fractf(ua0), __builtin_amdgcn_fractf(ua1) };
    f32x2 frB = { __builtin_amdgcn_fractf(ub0), __builtin_amdgcn_fractf(ub1) };

    const _Float16* baseA  = lds + (ia0 * 4) * LDS_PITCH + ia1 * 4;
    const _Float16* baseA2 = baseA + 2 * LDS_PITCH;
    const _Float16* baseB  = lds + (ib0 * 4) * LDS_PITCH + ib1 * 4;
    const _Float16* baseB2 = baseB + 2 * LDS_PITCH;

    // ---- 12 gathers, program-order adjacent ----
    half4_t la0 = *(const half4_t*)(baseA);
    half4_t la1 = *(const half4_t*)(baseA + LDS_PITCH);
    half4_t la2 = *(const half4_t*)(baseA2);
    half4_t la3 = *(const half4_t*)(baseA2 + LDS_PITCH);
    half4_t la4 = *(const half4_t*)(baseA2 + 2 * LDS_PITCH);
    half2_t ha0 = *(const half2_t*)(baseA + 4);
    half2_t ha1 = *(const half2_t*)(baseA + LDS_PITCH + 4);
    half2_t ha2 = *(const half2_t*)(baseA2 + 4);
    half2_t ha3 = *(const half2_t*)(baseA2 + LDS_PITCH + 4);
    half2_t ha4 = *(const half2_t*)(baseA2 + 2 * LDS_PITCH + 4);

    half4_t lb0 = *(const half4_t*)(baseB);
    half4_t lb1 = *(const half4_t*)(baseB + LDS_PITCH);
    half4_t lb2 = *(const half4_t*)(baseB2);
    half4_t lb3 = *(const half4_t*)(baseB2 + LDS_PITCH);
    half4_t lb4 = *(const half4_t*)(baseB2 + 2 * LDS_PITCH);
    half2_t hb0 = *(const half2_t*)(baseB + 4);
    half2_t hb1 = *(const half2_t*)(baseB + LDS_PITCH + 4);
    half2_t hb2 = *(const half2_t*)(baseB2 + 4);
    half2_t hb3 = *(const half2_t*)(baseB2 + LDS_PITCH + 4);
    half2_t hb4 = *(const half2_t*)(baseB2 + 2 * LDS_PITCH + 4);

    // ---- bases for both points (VALU overlaps DS latency) ----
    f32x2 nA[5], nB[5];
    nbasis(frA, nA);
    nbasis(frB, nB);
    half2_t qA01 = pack2(nA[0][1], nA[1][1]);
    half2_t qA23 = pack2(nA[2][1], nA[3][1]);
    float   bA4  = nA[4][1];
    half2_t qB01 = pack2(nB[0][1], nB[1][1]);
    half2_t qB23 = pack2(nB[2][1], nB[3][1]);
    float   bB4  = nB[4][1];

    half4_t loA[5] = { la0, la1, la2, la3, la4 };
    half2_t hiA[5] = { ha0, ha1, ha2, ha3, ha4 };
    half4_t loB[5] = { lb0, lb1, lb2, lb3, lb4 };
    half2_t hiB[5] = { hb0, hb1, hb2, hb3, hb4 };

    float rdA[5], rdB[5];
#pragma unroll
    for (int i = 0; i < 5; ++i) {
        half2_t xy = __builtin_shufflevector(loA[i], loA[i], 0, 1);
        half2_t zw = __builtin_shufflevector(loA[i], loA[i], 2, 3);
        float r = (float)hiA[i][0] * bA4;
        r = __builtin_amdgcn_fdot2(zw, qA23, r, false);
        r = __builtin_amdgcn_fdot2(xy, qA01, r, false);
        rdA[i] = r;
    }
#pragma unroll
    for (int i = 0; i < 5; ++i) {
        half2_t xy = __builtin_shufflevector(loB[i], loB[i], 0, 1);
        half2_t zw = __builtin_shufflevector(loB[i], loB[i], 2, 3);
        float r = (float)hiB[i][0] * bB4;
        r = __builtin_amdgcn_fdot2(zw, qB23, r, false);
        r = __builtin_amdgcn_fdot2(xy, qB01, r, false);
        rdB[i] = r;
    }

    float accA = nA[4][0] * rdA[4];
    accA = fmaf(nA[0][0], rdA[0], accA);
    accA = fmaf(nA[2][0], rdA[2], accA);
    float accA2 = nA[1][0] * rdA[1];
    accA2 = fmaf(nA[3][0], rdA[3], accA2);

    float accB = nB[4][0] * rdB[4];
    accB = fmaf(nB[0][0], rdB[0], accB);
    accB = fmaf(nB[2][0], rdB[2], accB);
    float accB2 = nB[1][0] * rdB[1];
    accB2 = fmaf(nB[3][0], rdB[3], accB2);

    float2 r;
    r.x = accA + accA2;
    r.y = accB + accB2;
    return r;
}

__launch_bounds__(BLOCK, 4)   // VGPR<=128; single 133KB-LDS block, 16 waves/CU
__global__ void lagrange_kernel(const float* __restrict__ inputs,
                                const float* __restrict__ coe,
                                float* __restrict__ out,
                                int npts) {
    extern __shared__ _Float16 lds[];
    const int t = threadIdx.x;
    const int tid = blockIdx.x * BLOCK + t;
    const int stride = GRID * BLOCK;
    const float2* __restrict__ in2 = (const float2*)inputs;  // 1 point / float2
    (void)npts;   // npts == GRID*BLOCK*16 exactly -> no bounds checks

    // ---- T14 issue-early: input-stream prefetch BEFORE staging ----
    // Cold-HBM latency of these 6 loads (~900 cyc each, post-poison) overlaps
    // the whole staging phase instead of stalling iterations 0-2 after the barrier.
    float2 a0 = in2[tid];
    float2 a1 = in2[tid + stride];
    float2 a2 = in2[tid + 2 * stride];
    float2 b0 = in2[tid + OUTER * stride];
    float2 b1 = in2[tid + (OUTER + 1) * stride];
    float2 b2 = in2[tid + (OUTER + 2) * stride];

    // ---- staging: ALL loads issued first (16-deep MLP + tails), then cvt+write ----
    // Tail loads go first: the col-256 gather (257 scattered lines) is the
    // longest-latency staging op; give it maximum overlap.
    float tail_col = 0.0f;
    if (t < NGRID) tail_col = coe[t * NGRID + 256];
    f4u qr;
    if (t < 64) qr = *(const f4u*)(coe + 256 * NGRID + (t << 2));
    f4u q[16];
#pragma unroll
    for (int k = 0; k < 16; ++k) {
        int g = t + k * BLOCK;          // 0..16383: rows 0..255 complete
        q[k] = *(const f4u*)(coe + (g >> 6) * NGRID + ((g & 63) << 2));
    }
    // Converts + LDS writes: denominator folding (R2, neutral-verified):
    // stored value = coe * s(row&3) * s(col&3), s = [1/24, -1/6, 1/4, -1/6].
#pragma unroll
    for (int k = 0; k < 16; ++k) {
        int g = t + k * BLOCK;
        int r = g >> 6;
        int c4 = (g & 63) << 2;
        float rs = rowscale(r);
        half4_t h = { (_Float16)(q[k].x * (rs * (1.0f / 24.0f))),
                      (_Float16)(q[k].y * (rs * (-1.0f / 6.0f))),
                      (_Float16)(q[k].z * (rs * 0.25f)),
                      (_Float16)(q[k].w * (rs * (-1.0f / 6.0f))) };
        *(half4_t*)(lds + r * LDS_PITCH + c4) = h;
    }
    if (t < 64) {                       // row 256 (scale 1/24), quads 0..63
        const float rs = 1.0f / 24.0f;
        half4_t h = { (_Float16)(qr.x * (rs * (1.0f / 24.0f))),
                      (_Float16)(qr.y * (rs * (-1.0f / 6.0f))),
                      (_Float16)(qr.z * (rs * 0.25f)),
                      (_Float16)(qr.w * (rs * (-1.0f / 6.0f))) };
        *(half4_t*)(lds + 256 * LDS_PITCH + (t << 2)) = h;
    }
    if (t < NGRID) {                    // column 256 (scale 1/24), all 257 rows
        float rs = rowscale(t);
        lds[t * LDS_PITCH + 256] = (_Float16)(tail_col * (rs * (1.0f / 24.0f)));
    }
    __syncthreads();

    // Two point streams (k and k+OUTER), 3-deep input prefetch each.
#pragma unroll
    for (int k = 0; k < OUTER; ++k) {
        float2 a3, b3;
        if (k + 3 < OUTER) {
            a3 = in2[tid + (k + 3) * stride];
            b3 = in2[tid + (k + OUTER + 3) * stride];
        }
        float2 r = eval2(lds, a0.x, a0.y, b0.x, b0.y);
        __builtin_nontemporal_store(r.x, &out[tid + k * stride]);
        __builtin_nontemporal_store(r.y, &out[tid + (k + OUTER) * stride]);
        a0 = a1; a1 = a2; a2 = a3;
        b0 = b1; b1 = b2; b2 = b3;
    }
}

extern "C" void kernel_launch(void* const* d_in, const int* in_sizes, int n_in,
                              void* d_out, int out_size, void* d_ws, size_t ws_size,
                              hipStream_t stream) {
    const float* inputs = (const float*)d_in[0];   // (2048,2048,2) f32
    const float* coe    = (const float*)d_in[1];   // (257,257) f32
    float* out = (float*)d_out;                    // (2048,2048) f32
    int npts = out_size;                           // 4,194,304

    (void)hipFuncSetAttribute((const void*)lagrange_kernel,
                              hipFuncAttributeMaxDynamicSharedMemorySize,
                              LDS_BYTES);

    dim3 grid(GRID), block(BLOCK);   // 1 block/CU (LDS-limited), 16 waves/CU
    hipLaunchKernelGGL(lagrange_kernel, grid, block, LDS_BYTES, stream,
                       inputs, coe, out, npts);
}